// Round 2
// baseline (616.615 us; speedup 1.0000x reference)
//
#include <hip/hip_runtime.h>
#include <math.h>

#define N_NODES 100000
#define DEG_E   32
#define T_CH    16
#define E_EDGES (N_NODES * DEG_E)

// ---------------- transpose x [T,N] -> xt [N,T] ----------------
__global__ void k_transpose_in(const float* __restrict__ x, float* __restrict__ xt) {
    int idx = blockIdx.x * blockDim.x + threadIdx.x;
    if (idx >= N_NODES * T_CH) return;
    int t = idx / N_NODES;
    int n = idx - t * N_NODES;
    xt[n * T_CH + t] = x[idx];
}

// ---------------- out-degree histogram over src (run-length compressed) ------
__global__ void k_degree(const int* __restrict__ src, int* __restrict__ deg, int E) {
    int chunk = blockIdx.x * blockDim.x + threadIdx.x;
    int e0 = chunk * DEG_E;
    if (e0 >= E) return;
    int e1 = min(e0 + DEG_E, E);
    int cur = src[e0];
    int cnt = 1;
    for (int e = e0 + 1; e < e1; ++e) {
        int s = src[e];
        if (s == cur) { cnt++; }
        else { atomicAdd(&deg[cur], cnt); cur = s; cnt = 1; }
    }
    atomicAdd(&deg[cur], cnt);
}

// ---------------- in-degree histogram over dst -------------------------------
__global__ void k_hist_dst(const int* __restrict__ dst, int* __restrict__ in_cnt) {
    int e = blockIdx.x * blockDim.x + threadIdx.x;
    if (e >= E_EDGES) return;
    atomicAdd(&in_cnt[dst[e]], 1);
}

// ---------------- bucket offset allocation (order-free exclusive "scan") -----
__global__ void k_alloc(const int* __restrict__ in_cnt, int* __restrict__ off,
                        int* __restrict__ cur, int* __restrict__ cursor) {
    int n = blockIdx.x * blockDim.x + threadIdx.x;
    if (n >= N_NODES) return;
    int o = atomicAdd(cursor, in_cnt[n]);
    off[n] = o;
    cur[n] = o;
}

// ---------------- fill CSR srclist by dst ------------------------------------
__global__ void k_fill(const int* __restrict__ src, const int* __restrict__ dst,
                       int* __restrict__ cur, int* __restrict__ srclist) {
    int e = blockIdx.x * blockDim.x + threadIdx.x;
    if (e >= E_EDGES) return;
    int d = dst[e];
    int pos = atomicAdd(&cur[d], 1);
    srclist[pos] = src[e];
}

// ---------------- fused gather + combine -------------------------------------
// 16 lanes per dst node; lane t owns channel t. Per in-edge: one coalesced
// 64B read of xt[src]. Then out = sw*deg^dp*xt[n] + nw*deg^(dp-1)*acc + b.
// FINAL=false: write [N,T] layout; FINAL=true: write [T,N] (d_out layout).
template <bool FINAL>
__global__ void k_gather_combine(const float* __restrict__ xt,
                                 const int* __restrict__ off,
                                 const int* __restrict__ in_cnt,
                                 const int* __restrict__ srclist,
                                 const int* __restrict__ deg,
                                 const float* __restrict__ alpha1,
                                 const float* __restrict__ gamma,
                                 const float* __restrict__ bias, int layer,
                                 float* __restrict__ outp) {
    int tid = blockIdx.x * blockDim.x + threadIdx.x;
    int n = tid >> 4;          // dst node
    int t = tid & 15;          // channel
    if (n >= N_NODES) return;

    int o = off[n];
    int c = in_cnt[n];
    float acc = 0.0f;
    #pragma unroll 4
    for (int i = 0; i < c; ++i) {
        int s = srclist[o + i];          // same addr across the 16 lanes -> 1 req
        acc += xt[s * T_CH + t];         // coalesced 64B per 16-lane group
    }

    float a1 = alpha1[layer];
    float g  = gamma[layer];
    float b  = bias[layer];
    float dp = 1.0f / (1.0f + __expf(-g));
    float sw = __expf(a1);
    float nw = sw * tanhf(a1);
    float ld = __logf((float)deg[n]);
    float w1 = __expf(dp * ld);          // deg^dp
    float w2 = __expf((dp - 1.0f) * ld); // deg^(dp-1)

    float v = sw * w1 * xt[n * T_CH + t] + nw * w2 * acc + b;
    if (FINAL) outp[t * N_NODES + n] = v;
    else       outp[n * T_CH + t] = v;
}

extern "C" void kernel_launch(void* const* d_in, const int* in_sizes, int n_in,
                              void* d_out, int out_size, void* d_ws, size_t ws_size,
                              hipStream_t stream) {
    const float* x      = (const float*)d_in[0];
    const int*   ei     = (const int*)d_in[1];
    const float* alpha1 = (const float*)d_in[2];
    const float* gamma  = (const float*)d_in[3];
    const float* bias   = (const float*)d_in[4];
    float* out = (float*)d_out;

    const int* src = ei;
    const int* dst = ei + E_EDGES;

    const int NT = N_NODES * T_CH;
    float* xtA     = (float*)d_ws;            // [N,T]  6.4 MB
    float* xtB     = xtA + NT;                // [N,T]  6.4 MB
    int*   srclist = (int*)(xtB + NT);        // [E]   12.8 MB
    int*   deg     = srclist + E_EDGES;       // [N]
    int*   in_cnt  = deg + N_NODES;           // [N]
    int*   off     = in_cnt + N_NODES;        // [N]
    int*   cur     = off + N_NODES;           // [N]
    int*   cursor  = cur + N_NODES;           // [1]

    const int B = 256;
    const int grid_nt  = (NT + B - 1) / B;
    const int grid_e   = (E_EDGES + B - 1) / B;
    const int grid_n   = (N_NODES + B - 1) / B;
    const int grid_deg = (E_EDGES / DEG_E + B - 1) / B;

    hipMemsetAsync(deg, 0, N_NODES * sizeof(int), stream);
    hipMemsetAsync(in_cnt, 0, N_NODES * sizeof(int), stream);
    hipMemsetAsync(cursor, 0, sizeof(int), stream);

    k_transpose_in<<<grid_nt, B, 0, stream>>>(x, xtA);
    k_degree<<<grid_deg, B, 0, stream>>>(src, deg, E_EDGES);
    k_hist_dst<<<grid_e, B, 0, stream>>>(dst, in_cnt);
    k_alloc<<<grid_n, B, 0, stream>>>(in_cnt, off, cur, cursor);
    k_fill<<<grid_e, B, 0, stream>>>(src, dst, cur, srclist);

    // layer 0: [N,T] -> [N,T]
    k_gather_combine<false><<<grid_nt, B, 0, stream>>>(
        xtA, off, in_cnt, srclist, deg, alpha1, gamma, bias, 0, xtB);
    // layer 1: [N,T] -> [T,N] (d_out)
    k_gather_combine<true><<<grid_nt, B, 0, stream>>>(
        xtB, off, in_cnt, srclist, deg, alpha1, gamma, bias, 1, out);
}